// Round 10
// baseline (327.930 us; speedup 1.0000x reference)
//
#include <hip/hip_runtime.h>

#define N_NODES 20000
#define N_PAD   20480   // 160 row-blocks of 128 -> exact 8-XCD partition (20 each)
#define N_EDGES 320000
#define F_IN 512
#define F_OUT 1024
#define N_GRAPHS 64
#define ESTRIDE 64      // fixed edge slots per node (P(deg>63) ~ 1e-20 for Poisson(16))

typedef __attribute__((ext_vector_type(8))) short bf16x8;
typedef __attribute__((ext_vector_type(4))) float f32x4;
typedef __attribute__((ext_vector_type(8))) unsigned short ushort8v;

static __device__ __forceinline__ unsigned short f2bf(float f) {
    unsigned int u = __float_as_uint(f);
    u = (u + 0x7fff + ((u >> 16) & 1)) >> 16;   // RNE
    return (unsigned short)u;
}
static __device__ __forceinline__ float bf2f(unsigned short s) {
    return __uint_as_float(((unsigned int)s) << 16);
}

// ---------------- setup: deg/cursor init + out zero + gstart + csre zero ----------------
__global__ void k_setup(float* deg, int* cursor, float* out,
                        const int* __restrict__ batch, int* gstart,
                        unsigned int* __restrict__ csre) {
    int i = blockIdx.x * 256 + threadIdx.x;   // grid covers 65536
    if (i < N_NODES) { deg[i] = 1.0f; cursor[i] = 0; }
    if (i < N_GRAPHS * F_OUT) out[i] = 0.f;
    if (i <= N_GRAPHS) {
        if (i == N_GRAPHS) gstart[i] = N_NODES;
        else {
            int lo = 0, hi = N_NODES;
            while (lo < hi) {
                int mid = (lo + hi) >> 1;
                if (batch[mid] < i) lo = mid + 1; else hi = mid;
            }
            gstart[i] = lo;
        }
    }
    // zero the edge table: padding slots must be (w=0, src=0) for the
    // pipelined aggr loop's zero-padded tail groups (w=0 -> safe row-0 read)
    for (int t = i; t < N_NODES * ESTRIDE; t += 65536) csre[t] = 0u;
}

// ---------------- fat pre-pass: deg atomics + W transposes + x conversion ----------------
#define NB_E    ((N_EDGES + 255) / 256)                 // 1250
#define NB_WT   ((F_OUT / 32) * (F_IN / 32 + F_OUT / 32)) // 32*48 = 1536
#define NB_CX   (N_PAD * (F_IN / 8) / 256)              // 5120
__global__ __launch_bounds__(256) void k_pre(const int* __restrict__ dst,
                                             const float* __restrict__ ew,
                                             float* deg,
                                             const float* __restrict__ W1,
                                             unsigned short* __restrict__ Wt1,
                                             const float* __restrict__ W2,
                                             unsigned short* __restrict__ Wt2,
                                             const float* __restrict__ x,
                                             unsigned short* __restrict__ xb) {
    __shared__ float tile[32][33];
    const int bid = blockIdx.x;
    if (bid < NB_E) {
        int e = bid * 256 + threadIdx.x;
        if (e < N_EDGES) atomicAdd(&deg[dst[e]], ew[e]);
    } else if (bid < NB_E + NB_WT) {
        int cid = bid - NB_E;
        int by = cid >> 5;          // 0..47
        int n0 = (cid & 31) * 32;
        const float* W; unsigned short* Wt; int K, k0;
        if (by < F_IN / 32) { W = W1; Wt = Wt1; K = F_IN;  k0 = by * 32; }
        else                { W = W2; Wt = Wt2; K = F_OUT; k0 = (by - F_IN / 32) * 32; }
        int tx = threadIdx.x & 31;
        int ty = threadIdx.x >> 5;
#pragma unroll
        for (int i = 0; i < 32; i += 8)
            tile[ty + i][tx] = W[(size_t)(k0 + ty + i) * F_OUT + n0 + tx];
        __syncthreads();
#pragma unroll
        for (int i = 0; i < 32; i += 8)
            Wt[(size_t)(n0 + ty + i) * K + k0 + tx] = f2bf(tile[tx][ty + i]);
    } else {
        int idx = (bid - NB_E - NB_WT) * 256 + threadIdx.x;  // one thread = 8 cols
        int row = idx >> 6;
        int c8 = (idx & 63) * 8;
        if (row >= N_PAD) return;
        ushort8v v;
        if (row < N_NODES) {
            const float* p = &x[(size_t)row * F_IN + c8];
#pragma unroll
            for (int i = 0; i < 8; i++) v[i] = f2bf(p[i]);
        } else {
#pragma unroll
            for (int i = 0; i < 8; i++) v[i] = 0;
        }
        *(ushort8v*)&xb[(size_t)row * F_IN + c8] = v;
    }
}

// ---------------- direct-slot packed edge table: csre[d*64+pos] = (w_bf16<<16)|src ----------------
__global__ void k_fill(const int* __restrict__ src, const int* __restrict__ dst,
                       const float* __restrict__ ew, const float* __restrict__ deg,
                       int* cursor, unsigned int* __restrict__ csre) {
    int e = blockIdx.x * 256 + threadIdx.x;
    if (e < N_EDGES) {
        int d = dst[e], s = src[e];
        int pos = atomicAdd(&cursor[d], 1);
        if (pos < ESTRIDE) {
            float w = rsqrtf(deg[s]) * ew[e] * rsqrtf(deg[d]);
            csre[d * ESTRIDE + pos] = ((unsigned int)f2bf(w) << 16) | (unsigned int)s;
        }
    }
}

// ---------------- slab aggregation, 4-wave blocks, pipelined + 32-bit saddr gathers ----
// Wave = 8 nodes x one 64-col slab (L2-resident footprint, r6 lesson); 2-deep
// pipelined edge loop (r9: VALUBusy 55->67). r9 diagnosis: VALU-ISSUE-bound
// (~46M wave-instrs vs ~25M core math) -> strength-reduce addressing:
// F*2 is a power of two -> 32-bit byte offset (row<<shB)+c2 (2-3 VALU, saddr
// global_load) instead of 64-bit mul chains; w = m&0xFFFF0000 (1 instr).
__global__ __launch_bounds__(256) void k_aggr_slab(const unsigned short* __restrict__ xin,
                                                   const float* __restrict__ deg,
                                                   const int* __restrict__ cursor,
                                                   const unsigned int* __restrict__ csre,
                                                   const float* __restrict__ bias,
                                                   unsigned short* __restrict__ outp,
                                                   int F, int act) {
    const int bid = blockIdx.x;
    const int slab = bid & 7;
    const int ng = (bid >> 3) * 4 + (threadIdx.x >> 6);   // wave w -> node-group
    const int lane = threadIdx.x & 63;
    const int n = ng * 8 + (lane >> 3);
    const int c = blockIdx.y * 512 + slab * 64 + (lane & 7) * 8;

    if (n >= N_NODES) {
        ushort8v z;
#pragma unroll
        for (int i = 0; i < 8; i++) z[i] = 0;
        *(ushort8v*)&outp[(size_t)n * F + c] = z;
        return;
    }

    const char* xb_ = (const char*)xin;
    const unsigned shB = (F == 512) ? 10u : 11u;    // log2(F*2): row -> byte offset
    const unsigned c2 = (unsigned)(c * 2);

    const float di = rsqrtf(deg[n]);
    const float wself = di * di;
    float a[8];
    {
        ushort8v v = *(const ushort8v*)(xb_ + (((unsigned)n << shB) + c2));
#pragma unroll
        for (int i = 0; i < 8; i++) a[i] = bf2f(v[i]) * wself;
    }

    const unsigned int* ce = csre + (size_t)n * ESTRIDE;   // 256B-aligned
    const int cnt = min(cursor[n], ESTRIDE);
    const int cnt4 = (cnt + 3) & ~3;                       // zero-padded full groups

    if (cnt4 > 0) {
        // prologue: meta(G0), meta(G1), rows(G0)
        uint4 m0 = *(const uint4*)&ce[0];
        uint4 m1 = (4 < cnt4) ? *(const uint4*)&ce[4] : m0;
        ushort8v u0 = *(const ushort8v*)(xb_ + (((m0.x & 0xFFFFu) << shB) + c2));
        ushort8v u1 = *(const ushort8v*)(xb_ + (((m0.y & 0xFFFFu) << shB) + c2));
        ushort8v u2 = *(const ushort8v*)(xb_ + (((m0.z & 0xFFFFu) << shB) + c2));
        ushort8v u3 = *(const ushort8v*)(xb_ + (((m0.w & 0xFFFFu) << shB) + c2));

        for (int j = 4; j < cnt4; j += 4) {
            // issue rows of group j (meta m1 already resident)
            ushort8v v0 = *(const ushort8v*)(xb_ + (((m1.x & 0xFFFFu) << shB) + c2));
            ushort8v v1 = *(const ushort8v*)(xb_ + (((m1.y & 0xFFFFu) << shB) + c2));
            ushort8v v2 = *(const ushort8v*)(xb_ + (((m1.z & 0xFFFFu) << shB) + c2));
            ushort8v v3 = *(const ushort8v*)(xb_ + (((m1.w & 0xFFFFu) << shB) + c2));
            // prefetch meta of group j+4 (clamped: re-read ce[0], discarded)
            const int jn = (j + 4 < cnt4) ? j + 4 : 0;
            uint4 m2 = *(const uint4*)&ce[jn];
            // compute group j-4 (overlaps the v* gathers in flight)
            {
                float w0 = __uint_as_float(m0.x & 0xFFFF0000u);
                float w1 = __uint_as_float(m0.y & 0xFFFF0000u);
                float w2 = __uint_as_float(m0.z & 0xFFFF0000u);
                float w3 = __uint_as_float(m0.w & 0xFFFF0000u);
#pragma unroll
                for (int i = 0; i < 8; i++) {
                    a[i] += w0 * bf2f(u0[i]);
                    a[i] += w1 * bf2f(u1[i]);
                    a[i] += w2 * bf2f(u2[i]);
                    a[i] += w3 * bf2f(u3[i]);
                }
            }
            m0 = m1; m1 = m2;
            u0 = v0; u1 = v1; u2 = v2; u3 = v3;
        }
        // epilogue: compute last group
        {
            float w0 = __uint_as_float(m0.x & 0xFFFF0000u);
            float w1 = __uint_as_float(m0.y & 0xFFFF0000u);
            float w2 = __uint_as_float(m0.z & 0xFFFF0000u);
            float w3 = __uint_as_float(m0.w & 0xFFFF0000u);
#pragma unroll
            for (int i = 0; i < 8; i++) {
                a[i] += w0 * bf2f(u0[i]);
                a[i] += w1 * bf2f(u1[i]);
                a[i] += w2 * bf2f(u2[i]);
                a[i] += w3 * bf2f(u3[i]);
            }
        }
    }

    ushort8v r;
    if (act) {
#pragma unroll
        for (int i = 0; i < 8; i++) r[i] = f2bf(fmaxf(a[i] + bias[c + i], 0.f));
    } else {
#pragma unroll
        for (int i = 0; i < 8; i++) r[i] = f2bf(a[i]);
    }
    *(ushort8v*)&outp[(size_t)n * F + c] = r;
}

// ---------------- single-buffer bf16 MFMA GEMM, BM=128 x BN=256 ----------------
// Merges two independently harness-verified pieces: r1's 512-thread 8-wave
// (2M x 4N) BN=256 geometry/fragment mapping (passed, 0 bank conflicts) with
// r9's single-buffer two-syncthreads schedule (session-best GEMM). B-panel
// serves 2x output -> stage bytes/MAC x0.75; 16 waves/CU (2 blocks x 8 waves)
// vs 12 before. LDS 48KB single buffer. __launch_bounds__(512,2): reg cap 256
// -> no spill possible (r4 lesson); grid 640 = 160 row-blocks x 4 col-blocks.
__global__ __launch_bounds__(512, 2) void k_gemm_sb(const unsigned short* __restrict__ A,
                                                    const unsigned short* __restrict__ Bt,
                                                    unsigned short* __restrict__ C, int K,
                                                    const float* __restrict__ bias, int act) {
    __shared__ short As[128 * 64];   // 16 KB
    __shared__ short Bs[256 * 64];   // 32 KB
    const int bid = blockIdx.x;
    const int xcd = bid & 7;
    const int i2 = bid >> 3;                 // 0..79 per XCD
    const int colb = i2 & 3;                 // col-fastest: A row-panel L2-resident
    const int rowb = xcd * 20 + (i2 >> 2);   // exact partition: 8 XCD x 20 row-blocks
    const int row0 = rowb * 128;
    const int col0 = colb * 256;

    const int tid = threadIdx.x;
    const int lane = tid & 63;
    const int wave = tid >> 6;          // 0..7
    const int wm = wave >> 2;           // 0..1  (row half of BM=128)
    const int wn = wave & 3;            // 0..3  (64-col strip of BN=256)
    const int l16 = lane & 15;
    const int kq = lane >> 4;           // 0..3  (8-elem k-granule within a 32-k step)

    const int NT = K >> 6;
    f32x4 acc[4][4] = {};               // [fr][fc] 16x16 fragments

    for (int t = 0; t < NT; ++t) {
        const int k0 = t * 64;
#pragma unroll
        for (int it = 0; it < 2; it++) {       // A: 1024 granules
            int q = it * 512 + tid;
            int r = q >> 3;
            int g = (q & 7) ^ (r & 7);         // source pre-swizzled for lane-linear dest
            __builtin_amdgcn_global_load_lds(
                (const __attribute__((address_space(1))) void*)&A[(size_t)(row0 + r) * K + k0 + g * 8],
                (__attribute__((address_space(3))) void*)&As[q * 8], 16, 0, 0);
        }
#pragma unroll
        for (int it = 0; it < 4; it++) {       // B: 2048 granules
            int q = it * 512 + tid;
            int r = q >> 3;
            int g = (q & 7) ^ (r & 7);
            __builtin_amdgcn_global_load_lds(
                (const __attribute__((address_space(1))) void*)&Bt[(size_t)(col0 + r) * K + k0 + g * 8],
                (__attribute__((address_space(3))) void*)&Bs[q * 8], 16, 0, 0);
        }
        __syncthreads();

#pragma unroll
        for (int ks = 0; ks < 2; ks++) {
            bf16x8 af[4], bfr[4];
#pragma unroll
            for (int fr = 0; fr < 4; fr++) {
                int r = wm * 64 + fr * 16 + l16;
                int g = (ks * 4 + kq) ^ (r & 7);
                af[fr] = *(const bf16x8*)&As[(r * 8 + g) * 8];
            }
#pragma unroll
            for (int fc = 0; fc < 4; fc++) {
                int r = wn * 64 + fc * 16 + l16;
                int g = (ks * 4 + kq) ^ (r & 7);
                bfr[fc] = *(const bf16x8*)&Bs[(r * 8 + g) * 8];
            }
            __builtin_amdgcn_s_setprio(1);
#pragma unroll
            for (int fr = 0; fr < 4; fr++)
#pragma unroll
                for (int fc = 0; fc < 4; fc++)
                    acc[fr][fc] = __builtin_amdgcn_mfma_f32_16x16x32_bf16(
                        af[fr], bfr[fc], acc[fr][fc], 0, 0, 0);
            __builtin_amdgcn_s_setprio(0);
        }
        __syncthreads();
    }

    // C/D (16x16x32): row = (lane>>4)*4 + reg (M side), col = lane&15 (N side)  [m89]
#pragma unroll
    for (int fr = 0; fr < 4; fr++) {
        int m0 = row0 + wm * 64 + fr * 16 + kq * 4;
#pragma unroll
        for (int fc = 0; fc < 4; fc++) {
            int n = col0 + wn * 64 + fc * 16 + l16;
            float bv = act ? bias[n] : 0.f;
#pragma unroll
            for (int reg = 0; reg < 4; reg++) {
                float v = acc[fr][fc][reg];
                if (act) v = fmaxf(v + bv, 0.f);
                C[(size_t)(m0 + reg) * F_OUT + n] = f2bf(v);
            }
        }
    }
}

// ---------------- atomic-free mean-pool: 1 wave per (graph, 64-col slab) ----------------
__global__ __launch_bounds__(64) void k_pool_g(const unsigned short* __restrict__ h,
                                               const int* __restrict__ gstart,
                                               float* __restrict__ out) {
    const int g = blockIdx.x >> 4;            // 64 graphs
    const int slab = blockIdx.x & 15;         // 16 slabs x 64 cols
    const int lane = threadIdx.x;
    const int c = slab * 64 + (lane & 7) * 8;
    const int r0 = gstart[g], r1 = gstart[g + 1];

    float a[8] = {};
    for (int r = r0 + (lane >> 3); r < r1; r += 8) {
        ushort8v v = *(const ushort8v*)&h[(size_t)r * F_OUT + c];
#pragma unroll
        for (int i = 0; i < 8; i++) a[i] += bf2f(v[i]);
    }
#pragma unroll
    for (int m = 8; m < 64; m <<= 1)
#pragma unroll
        for (int i = 0; i < 8; i++) a[i] += __shfl_xor(a[i], m, 64);

    if ((lane >> 3) == 0) {
        const float inv = 1.0f / (float)max(r1 - r0, 1);
#pragma unroll
        for (int i = 0; i < 8; i++)
            out[(size_t)g * F_OUT + c + i] = a[i] * inv;
    }
}

// ---------------- launch ----------------
extern "C" void kernel_launch(void* const* d_in, const int* in_sizes, int n_in,
                              void* d_out, int out_size, void* d_ws, size_t ws_size,
                              hipStream_t stream) {
    const float* x    = (const float*)d_in[0];
    const int* ei     = (const int*)d_in[1];
    const float* ew   = (const float*)d_in[2];
    const int* batch  = (const int*)d_in[3];
    const float* W1   = (const float*)d_in[4];
    const float* b1   = (const float*)d_in[5];
    const float* W2   = (const float*)d_in[6];
    const float* b2   = (const float*)d_in[7];
    float* out = (float*)d_out;

    const int* src = ei;
    const int* dst = ei + N_EDGES;

    char* ws = (char*)d_ws;
    const size_t SZ_XB  = (size_t)N_PAD * F_IN * 2;    // 21.0 MB
    const size_t SZ_AX  = (size_t)N_PAD * F_IN * 2;    // 21.0 MB
    const size_t SZ_WT1 = (size_t)F_OUT * F_IN * 2;    //  1 MB
    const size_t SZ_WT2 = (size_t)F_OUT * F_OUT * 2;   //  2 MB
    const size_t SZ_B   = (size_t)N_PAD * F_OUT * 2;   // 41.9 MB
    unsigned short* xb  = (unsigned short*)(ws);
    unsigned short* ax  = (unsigned short*)(ws + SZ_XB);
    unsigned short* Wt1 = (unsigned short*)(ws + SZ_XB + SZ_AX);
    unsigned short* Wt2 = (unsigned short*)(ws + SZ_XB + SZ_AX + SZ_WT1);
    unsigned short* h1  = (unsigned short*)(ws + SZ_XB + SZ_AX + SZ_WT1 + SZ_WT2);
    unsigned short* xw2 = (unsigned short*)(ws + SZ_XB + SZ_AX + SZ_WT1 + SZ_WT2 + SZ_B);
    unsigned short* h2  = (unsigned short*)(ws);       // aliases xb/ax (dead in phase B)
    size_t off = SZ_XB + SZ_AX + SZ_WT1 + SZ_WT2 + 2 * SZ_B;
    auto alloc = [&](size_t bytes) -> void* {
        void* p = ws + off;
        off += (bytes + 255) & ~(size_t)255;
        return p;
    };
    float*        deg    = (float*)       alloc((size_t)N_NODES * 4);
    int*          cursor = (int*)         alloc((size_t)N_NODES * 4);
    unsigned int* csre   = (unsigned int*)alloc((size_t)N_NODES * ESTRIDE * 4);  // 5.12 MB
    int*          gstart = (int*)         alloc((size_t)(N_GRAPHS + 1) * 4);

    // 1. setup (deg=1, cursor=0, out=0, gstart, csre zero)
    k_setup<<<(N_GRAPHS * F_OUT + 255) / 256, 256, 0, stream>>>(deg, cursor, out, batch, gstart, csre);
    // 2. fat pre-pass: deg atomics + both W transposes + x->bf16
    k_pre<<<NB_E + NB_WT + NB_CX, 256, 0, stream>>>(dst, ew, deg, W1, Wt1, W2, Wt2, x, xb);
    // 3. packed direct-slot edge table (scan eliminated)
    k_fill<<<NB_E, 256, 0, stream>>>(src, dst, ew, deg, cursor, csre);
    // 4. layer-1 aggregation (4-wave blocks, pipelined, saddr gathers)
    k_aggr_slab<<<dim3((N_PAD / 32) * 8, 1), 256, 0, stream>>>(xb, deg, cursor, csre,
                                                               (const float*)nullptr, ax, F_IN, 0);
    // 5/6. GEMMs: 128x256 single-buffer, 512 threads, 640 blocks
    const int gemm_blocks = (N_PAD / 128) * (F_OUT / 256);   // 640
    k_gemm_sb<<<gemm_blocks, 512, 0, stream>>>(ax, Wt1, h1, F_IN, b1, 1);
    k_gemm_sb<<<gemm_blocks, 512, 0, stream>>>(h1, Wt2, xw2, F_OUT, (const float*)nullptr, 0);
    // 7. layer-2 aggregation + bias + relu -> h2
    k_aggr_slab<<<dim3((N_PAD / 32) * 8, 2), 256, 0, stream>>>(xw2, deg, cursor, csre, b2, h2, F_OUT, 1);
    // 8. atomic-free pool (1 wave per graph x slab)
    k_pool_g<<<N_GRAPHS * 16, 64, 0, stream>>>(h2, gstart, out);
}

// Round 11
// 309.276 us; speedup vs baseline: 1.0603x; 1.0603x over previous
//
#include <hip/hip_runtime.h>

#define N_NODES 20000
#define N_PAD   20480   // 160 row-blocks of 128 -> exact 8-XCD partition (20 each)
#define N_EDGES 320000
#define F_IN 512
#define F_OUT 1024
#define N_GRAPHS 64
#define ESTRIDE 64      // fixed edge slots per node (P(deg>63) ~ 1e-20 for Poisson(16))

typedef __attribute__((ext_vector_type(8))) short bf16x8;
typedef __attribute__((ext_vector_type(4))) float f32x4;
typedef __attribute__((ext_vector_type(8))) unsigned short ushort8v;

static __device__ __forceinline__ unsigned short f2bf(float f) {
    unsigned int u = __float_as_uint(f);
    u = (u + 0x7fff + ((u >> 16) & 1)) >> 16;   // RNE
    return (unsigned short)u;
}
static __device__ __forceinline__ float bf2f(unsigned short s) {
    return __uint_as_float(((unsigned int)s) << 16);
}

// ---------------- setup: deg/cursor init + out zero + gstart + csre zero ----------------
__global__ void k_setup(float* deg, int* cursor, float* out,
                        const int* __restrict__ batch, int* gstart,
                        unsigned int* __restrict__ csre) {
    int i = blockIdx.x * 256 + threadIdx.x;   // grid covers 65536
    if (i < N_NODES) { deg[i] = 1.0f; cursor[i] = 0; }
    if (i < N_GRAPHS * F_OUT) out[i] = 0.f;
    if (i <= N_GRAPHS) {
        if (i == N_GRAPHS) gstart[i] = N_NODES;
        else {
            int lo = 0, hi = N_NODES;
            while (lo < hi) {
                int mid = (lo + hi) >> 1;
                if (batch[mid] < i) lo = mid + 1; else hi = mid;
            }
            gstart[i] = lo;
        }
    }
    // zero the edge table: padding slots must be (w=0, src=0) for the
    // pipelined aggr loop's zero-padded tail groups (w=0 -> safe row-0 read)
    for (int t = i; t < N_NODES * ESTRIDE; t += 65536) csre[t] = 0u;
}

// ---------------- fat pre-pass: deg atomics + W transposes + x conversion ----------------
#define NB_E    ((N_EDGES + 255) / 256)                 // 1250
#define NB_WT   ((F_OUT / 32) * (F_IN / 32 + F_OUT / 32)) // 32*48 = 1536
#define NB_CX   (N_PAD * (F_IN / 8) / 256)              // 5120
__global__ __launch_bounds__(256) void k_pre(const int* __restrict__ dst,
                                             const float* __restrict__ ew,
                                             float* deg,
                                             const float* __restrict__ W1,
                                             unsigned short* __restrict__ Wt1,
                                             const float* __restrict__ W2,
                                             unsigned short* __restrict__ Wt2,
                                             const float* __restrict__ x,
                                             unsigned short* __restrict__ xb) {
    __shared__ float tile[32][33];
    const int bid = blockIdx.x;
    if (bid < NB_E) {
        int e = bid * 256 + threadIdx.x;
        if (e < N_EDGES) atomicAdd(&deg[dst[e]], ew[e]);
    } else if (bid < NB_E + NB_WT) {
        int cid = bid - NB_E;
        int by = cid >> 5;          // 0..47
        int n0 = (cid & 31) * 32;
        const float* W; unsigned short* Wt; int K, k0;
        if (by < F_IN / 32) { W = W1; Wt = Wt1; K = F_IN;  k0 = by * 32; }
        else                { W = W2; Wt = Wt2; K = F_OUT; k0 = (by - F_IN / 32) * 32; }
        int tx = threadIdx.x & 31;
        int ty = threadIdx.x >> 5;
#pragma unroll
        for (int i = 0; i < 32; i += 8)
            tile[ty + i][tx] = W[(size_t)(k0 + ty + i) * F_OUT + n0 + tx];
        __syncthreads();
#pragma unroll
        for (int i = 0; i < 32; i += 8)
            Wt[(size_t)(n0 + ty + i) * K + k0 + tx] = f2bf(tile[tx][ty + i]);
    } else {
        int idx = (bid - NB_E - NB_WT) * 256 + threadIdx.x;  // one thread = 8 cols
        int row = idx >> 6;
        int c8 = (idx & 63) * 8;
        if (row >= N_PAD) return;
        ushort8v v;
        if (row < N_NODES) {
            const float* p = &x[(size_t)row * F_IN + c8];
#pragma unroll
            for (int i = 0; i < 8; i++) v[i] = f2bf(p[i]);
        } else {
#pragma unroll
            for (int i = 0; i < 8; i++) v[i] = 0;
        }
        *(ushort8v*)&xb[(size_t)row * F_IN + c8] = v;
    }
}

// ---------------- direct-slot packed edge table: csre[d*64+pos] = (w_bf16<<16)|src ----------------
__global__ void k_fill(const int* __restrict__ src, const int* __restrict__ dst,
                       const float* __restrict__ ew, const float* __restrict__ deg,
                       int* cursor, unsigned int* __restrict__ csre) {
    int e = blockIdx.x * 256 + threadIdx.x;
    if (e < N_EDGES) {
        int d = dst[e], s = src[e];
        int pos = atomicAdd(&cursor[d], 1);
        if (pos < ESTRIDE) {
            float w = rsqrtf(deg[s]) * ew[e] * rsqrtf(deg[d]);
            csre[d * ESTRIDE + pos] = ((unsigned int)f2bf(w) << 16) | (unsigned int)s;
        }
    }
}

// ---------------- slab aggregation, 4-wave blocks, pipelined + 32-bit saddr gathers ----
// Wave = 8 nodes x one 64-col slab (L2-resident footprint, r6 lesson); 2-deep
// pipelined edge loop (r9: VALUBusy 55->67); strength-reduced addressing
// (r10: 32-bit (row<<shB)+c2 byte offsets, w = m&0xFFFF0000).
__global__ __launch_bounds__(256) void k_aggr_slab(const unsigned short* __restrict__ xin,
                                                   const float* __restrict__ deg,
                                                   const int* __restrict__ cursor,
                                                   const unsigned int* __restrict__ csre,
                                                   const float* __restrict__ bias,
                                                   unsigned short* __restrict__ outp,
                                                   int F, int act) {
    const int bid = blockIdx.x;
    const int slab = bid & 7;
    const int ng = (bid >> 3) * 4 + (threadIdx.x >> 6);   // wave w -> node-group
    const int lane = threadIdx.x & 63;
    const int n = ng * 8 + (lane >> 3);
    const int c = blockIdx.y * 512 + slab * 64 + (lane & 7) * 8;

    if (n >= N_NODES) {
        ushort8v z;
#pragma unroll
        for (int i = 0; i < 8; i++) z[i] = 0;
        *(ushort8v*)&outp[(size_t)n * F + c] = z;
        return;
    }

    const char* xb_ = (const char*)xin;
    const unsigned shB = (F == 512) ? 10u : 11u;    // log2(F*2): row -> byte offset
    const unsigned c2 = (unsigned)(c * 2);

    const float di = rsqrtf(deg[n]);
    const float wself = di * di;
    float a[8];
    {
        ushort8v v = *(const ushort8v*)(xb_ + (((unsigned)n << shB) + c2));
#pragma unroll
        for (int i = 0; i < 8; i++) a[i] = bf2f(v[i]) * wself;
    }

    const unsigned int* ce = csre + (size_t)n * ESTRIDE;   // 256B-aligned
    const int cnt = min(cursor[n], ESTRIDE);
    const int cnt4 = (cnt + 3) & ~3;                       // zero-padded full groups

    if (cnt4 > 0) {
        // prologue: meta(G0), meta(G1), rows(G0)
        uint4 m0 = *(const uint4*)&ce[0];
        uint4 m1 = (4 < cnt4) ? *(const uint4*)&ce[4] : m0;
        ushort8v u0 = *(const ushort8v*)(xb_ + (((m0.x & 0xFFFFu) << shB) + c2));
        ushort8v u1 = *(const ushort8v*)(xb_ + (((m0.y & 0xFFFFu) << shB) + c2));
        ushort8v u2 = *(const ushort8v*)(xb_ + (((m0.z & 0xFFFFu) << shB) + c2));
        ushort8v u3 = *(const ushort8v*)(xb_ + (((m0.w & 0xFFFFu) << shB) + c2));

        for (int j = 4; j < cnt4; j += 4) {
            // issue rows of group j (meta m1 already resident)
            ushort8v v0 = *(const ushort8v*)(xb_ + (((m1.x & 0xFFFFu) << shB) + c2));
            ushort8v v1 = *(const ushort8v*)(xb_ + (((m1.y & 0xFFFFu) << shB) + c2));
            ushort8v v2 = *(const ushort8v*)(xb_ + (((m1.z & 0xFFFFu) << shB) + c2));
            ushort8v v3 = *(const ushort8v*)(xb_ + (((m1.w & 0xFFFFu) << shB) + c2));
            // prefetch meta of group j+4 (clamped: re-read ce[0], discarded)
            const int jn = (j + 4 < cnt4) ? j + 4 : 0;
            uint4 m2 = *(const uint4*)&ce[jn];
            // compute group j-4 (overlaps the v* gathers in flight)
            {
                float w0 = __uint_as_float(m0.x & 0xFFFF0000u);
                float w1 = __uint_as_float(m0.y & 0xFFFF0000u);
                float w2 = __uint_as_float(m0.z & 0xFFFF0000u);
                float w3 = __uint_as_float(m0.w & 0xFFFF0000u);
#pragma unroll
                for (int i = 0; i < 8; i++) {
                    a[i] += w0 * bf2f(u0[i]);
                    a[i] += w1 * bf2f(u1[i]);
                    a[i] += w2 * bf2f(u2[i]);
                    a[i] += w3 * bf2f(u3[i]);
                }
            }
            m0 = m1; m1 = m2;
            u0 = v0; u1 = v1; u2 = v2; u3 = v3;
        }
        // epilogue: compute last group
        {
            float w0 = __uint_as_float(m0.x & 0xFFFF0000u);
            float w1 = __uint_as_float(m0.y & 0xFFFF0000u);
            float w2 = __uint_as_float(m0.z & 0xFFFF0000u);
            float w3 = __uint_as_float(m0.w & 0xFFFF0000u);
#pragma unroll
            for (int i = 0; i < 8; i++) {
                a[i] += w0 * bf2f(u0[i]);
                a[i] += w1 * bf2f(u1[i]);
                a[i] += w2 * bf2f(u2[i]);
                a[i] += w3 * bf2f(u3[i]);
            }
        }
    }

    ushort8v r;
    if (act) {
#pragma unroll
        for (int i = 0; i < 8; i++) r[i] = f2bf(fmaxf(a[i] + bias[c + i], 0.f));
    } else {
#pragma unroll
        for (int i = 0; i < 8; i++) r[i] = f2bf(a[i]);
    }
    *(ushort8v*)&outp[(size_t)n * F + c] = r;
}

// ---------------- single-buffer bf16 MFMA GEMM (r9 session-best config, reverted) ----
// BM=BN=128, BK=64, 256 threads = 4 waves (2x2), per-wave C = 64x64 via 4x4
// 16x16x32 fragments (conflict-free: 0 SQ_LDS_BANK_CONFLICT). SINGLE 32 KB LDS
// buffer + two syncthreads per K-tile; 3 blocks/CU inter-block overlap (m114)
// is the proven winner at this shape: r1 ring-3 (1 blk) 78us, r3 dbuf (2 blk)
// 69us, r10 BN256 (2 blk, tail) 59us, THIS (3 blk) 56.7us.
// __launch_bounds__(256,3): cap 170 >= natural 128 unified -> no spill.
__global__ __launch_bounds__(256, 3) void k_gemm_sb(const unsigned short* __restrict__ A,
                                                    const unsigned short* __restrict__ Bt,
                                                    unsigned short* __restrict__ C, int K,
                                                    const float* __restrict__ bias, int act) {
    __shared__ short As[128 * 64];   // 16 KB
    __shared__ short Bs[128 * 64];   // 16 KB
    const int bid = blockIdx.x;
    const int xcd = bid & 7;
    const int i2 = bid >> 3;                 // 0..159
    const int colb = i2 & 7;                 // col-fastest: A row-panel L2-resident
    const int rowb = xcd * 20 + (i2 >> 3);   // exact partition: 8 XCD x 20 row-blocks
    const int row0 = rowb * 128;
    const int col0 = colb * 128;

    const int tid = threadIdx.x;
    const int lane = tid & 63;
    const int wave = tid >> 6;          // 0..3
    const int wm = wave >> 1, wn = wave & 1;
    const int l16 = lane & 15;
    const int kq = lane >> 4;           // 0..3  (8-elem k-granule within a 32-k step)

    const int NT = K >> 6;
    f32x4 acc[4][4] = {};               // [fr][fc] 16x16 fragments

    for (int t = 0; t < NT; ++t) {
        const int k0 = t * 64;
#pragma unroll
        for (int it = 0; it < 4; it++) {       // 1024 granules each of A and B
            int q = it * 256 + tid;
            int r = q >> 3;
            int g = (q & 7) ^ (r & 7);         // source pre-swizzled for lane-linear dest
            __builtin_amdgcn_global_load_lds(
                (const __attribute__((address_space(1))) void*)&A[(size_t)(row0 + r) * K + k0 + g * 8],
                (__attribute__((address_space(3))) void*)&As[q * 8], 16, 0, 0);
            __builtin_amdgcn_global_load_lds(
                (const __attribute__((address_space(1))) void*)&Bt[(size_t)(col0 + r) * K + k0 + g * 8],
                (__attribute__((address_space(3))) void*)&Bs[q * 8], 16, 0, 0);
        }
        __syncthreads();

#pragma unroll
        for (int ks = 0; ks < 2; ks++) {
            bf16x8 af[4], bfr[4];
#pragma unroll
            for (int fr = 0; fr < 4; fr++) {
                int r = wm * 64 + fr * 16 + l16;
                int g = (ks * 4 + kq) ^ (r & 7);
                af[fr] = *(const bf16x8*)&As[(r * 8 + g) * 8];
            }
#pragma unroll
            for (int fc = 0; fc < 4; fc++) {
                int r = wn * 64 + fc * 16 + l16;
                int g = (ks * 4 + kq) ^ (r & 7);
                bfr[fc] = *(const bf16x8*)&Bs[(r * 8 + g) * 8];
            }
            __builtin_amdgcn_s_setprio(1);
#pragma unroll
            for (int fr = 0; fr < 4; fr++)
#pragma unroll
                for (int fc = 0; fc < 4; fc++)
                    acc[fr][fc] = __builtin_amdgcn_mfma_f32_16x16x32_bf16(
                        af[fr], bfr[fc], acc[fr][fc], 0, 0, 0);
            __builtin_amdgcn_s_setprio(0);
        }
        __syncthreads();
    }

    // C/D (16x16x32): row = (lane>>4)*4 + reg (M side), col = lane&15 (N side)  [m89]
#pragma unroll
    for (int fr = 0; fr < 4; fr++) {
        int m0 = row0 + wm * 64 + fr * 16 + kq * 4;
#pragma unroll
        for (int fc = 0; fc < 4; fc++) {
            int n = col0 + wn * 64 + fc * 16 + l16;
            float bv = act ? bias[n] : 0.f;
#pragma unroll
            for (int reg = 0; reg < 4; reg++) {
                float v = acc[fr][fc][reg];
                if (act) v = fmaxf(v + bv, 0.f);
                C[(size_t)(m0 + reg) * F_OUT + n] = f2bf(v);
            }
        }
    }
}

// ---------------- atomic-free mean-pool: 1 wave per (graph, 64-col slab) ----------------
__global__ __launch_bounds__(64) void k_pool_g(const unsigned short* __restrict__ h,
                                               const int* __restrict__ gstart,
                                               float* __restrict__ out) {
    const int g = blockIdx.x >> 4;            // 64 graphs
    const int slab = blockIdx.x & 15;         // 16 slabs x 64 cols
    const int lane = threadIdx.x;
    const int c = slab * 64 + (lane & 7) * 8;
    const int r0 = gstart[g], r1 = gstart[g + 1];

    float a[8] = {};
    for (int r = r0 + (lane >> 3); r < r1; r += 8) {
        ushort8v v = *(const ushort8v*)&h[(size_t)r * F_OUT + c];
#pragma unroll
        for (int i = 0; i < 8; i++) a[i] += bf2f(v[i]);
    }
#pragma unroll
    for (int m = 8; m < 64; m <<= 1)
#pragma unroll
        for (int i = 0; i < 8; i++) a[i] += __shfl_xor(a[i], m, 64);

    if ((lane >> 3) == 0) {
        const float inv = 1.0f / (float)max(r1 - r0, 1);
#pragma unroll
        for (int i = 0; i < 8; i++)
            out[(size_t)g * F_OUT + c + i] = a[i] * inv;
    }
}

// ---------------- launch ----------------
extern "C" void kernel_launch(void* const* d_in, const int* in_sizes, int n_in,
                              void* d_out, int out_size, void* d_ws, size_t ws_size,
                              hipStream_t stream) {
    const float* x    = (const float*)d_in[0];
    const int* ei     = (const int*)d_in[1];
    const float* ew   = (const float*)d_in[2];
    const int* batch  = (const int*)d_in[3];
    const float* W1   = (const float*)d_in[4];
    const float* b1   = (const float*)d_in[5];
    const float* W2   = (const float*)d_in[6];
    const float* b2   = (const float*)d_in[7];
    float* out = (float*)d_out;

    const int* src = ei;
    const int* dst = ei + N_EDGES;

    char* ws = (char*)d_ws;
    const size_t SZ_XB  = (size_t)N_PAD * F_IN * 2;    // 21.0 MB
    const size_t SZ_AX  = (size_t)N_PAD * F_IN * 2;    // 21.0 MB
    const size_t SZ_WT1 = (size_t)F_OUT * F_IN * 2;    //  1 MB
    const size_t SZ_WT2 = (size_t)F_OUT * F_OUT * 2;   //  2 MB
    const size_t SZ_B   = (size_t)N_PAD * F_OUT * 2;   // 41.9 MB
    unsigned short* xb  = (unsigned short*)(ws);
    unsigned short* ax  = (unsigned short*)(ws + SZ_XB);
    unsigned short* Wt1 = (unsigned short*)(ws + SZ_XB + SZ_AX);
    unsigned short* Wt2 = (unsigned short*)(ws + SZ_XB + SZ_AX + SZ_WT1);
    unsigned short* h1  = (unsigned short*)(ws + SZ_XB + SZ_AX + SZ_WT1 + SZ_WT2);
    unsigned short* xw2 = (unsigned short*)(ws + SZ_XB + SZ_AX + SZ_WT1 + SZ_WT2 + SZ_B);
    unsigned short* h2  = (unsigned short*)(ws);       // aliases xb/ax (dead in phase B)
    size_t off = SZ_XB + SZ_AX + SZ_WT1 + SZ_WT2 + 2 * SZ_B;
    auto alloc = [&](size_t bytes) -> void* {
        void* p = ws + off;
        off += (bytes + 255) & ~(size_t)255;
        return p;
    };
    float*        deg    = (float*)       alloc((size_t)N_NODES * 4);
    int*          cursor = (int*)         alloc((size_t)N_NODES * 4);
    unsigned int* csre   = (unsigned int*)alloc((size_t)N_NODES * ESTRIDE * 4);  // 5.12 MB
    int*          gstart = (int*)         alloc((size_t)(N_GRAPHS + 1) * 4);

    // 1. setup (deg=1, cursor=0, out=0, gstart, csre zero)
    k_setup<<<(N_GRAPHS * F_OUT + 255) / 256, 256, 0, stream>>>(deg, cursor, out, batch, gstart, csre);
    // 2. fat pre-pass: deg atomics + both W transposes + x->bf16
    k_pre<<<NB_E + NB_WT + NB_CX, 256, 0, stream>>>(dst, ew, deg, W1, Wt1, W2, Wt2, x, xb);
    // 3. packed direct-slot edge table (scan eliminated)
    k_fill<<<NB_E, 256, 0, stream>>>(src, dst, ew, deg, cursor, csre);
    // 4. layer-1 aggregation (4-wave blocks, pipelined, saddr gathers)
    k_aggr_slab<<<dim3((N_PAD / 32) * 8, 1), 256, 0, stream>>>(xb, deg, cursor, csre,
                                                               (const float*)nullptr, ax, F_IN, 0);
    // 5/6. GEMMs: single-buffer 32KB, 3 blocks/CU, 1280 blocks (r9 best config)
    const int gemm_blocks = (N_PAD / 128) * (F_OUT / 128);   // 1280
    k_gemm_sb<<<gemm_blocks, 256, 0, stream>>>(ax, Wt1, h1, F_IN, b1, 1);
    k_gemm_sb<<<gemm_blocks, 256, 0, stream>>>(h1, Wt2, xw2, F_OUT, (const float*)nullptr, 0);
    // 7. layer-2 aggregation + bias + relu -> h2
    k_aggr_slab<<<dim3((N_PAD / 32) * 8, 2), 256, 0, stream>>>(xw2, deg, cursor, csre, b2, h2, F_OUT, 1);
    // 8. atomic-free pool (1 wave per graph x slab)
    k_pool_g<<<N_GRAPHS * 16, 64, 0, stream>>>(h2, gstart, out);
}